// Round 4
// baseline (684.129 us; speedup 1.0000x reference)
//
#include <hip/hip_runtime.h>
#include <math.h>

#define NF 24
#define NV 100000
#define ND 64
#define NP 276            // NF*(NF-1)/2
#define SPW 2             // samples per wave
#define NWAVES 4          // waves per block
#define BLOCK (NWAVES * 64)
#define SPB (SPW * NWAVES) // samples per block = 8
#define NB 8192

__global__ __launch_bounds__(BLOCK) void ofm_kernel(
    const int* __restrict__ x,
    const int* __restrict__ flagp,
    const float* __restrict__ emb2,
    const float* __restrict__ emb1,
    const float* __restrict__ biasp,
    const float* __restrict__ arch_w,
    float* __restrict__ out)
{
    __shared__ float2 c23[NP];   // (c2, c3) per pair
    __shared__ float  c1s[NP];
    __shared__ float  gs[NF];

    const int tid = threadIdx.x;

    // ---- phase 0: per-pair coefficients from arch_w (+ flag==0 one-hot path) ----
    const int flg = flagp[0];
    for (int p = tid; p < NP; p += BLOCK) {
        float w0 = arch_w[p*5+0], w1 = arch_w[p*5+1], w2 = arch_w[p*5+2],
              w3 = arch_w[p*5+3], w4 = arch_w[p*5+4];
        if (flg == 0) {
            int sel = 0; float m = w0;
            if (w1 > m) { m = w1; sel = 1; }
            if (w2 > m) { m = w2; sel = 2; }
            if (w3 > m) { m = w3; sel = 3; }
            if (w4 > m) { m = w4; sel = 4; }
            w0 = (sel==0) ? 1.f : 0.f; w1 = (sel==1) ? 1.f : 0.f;
            w2 = (sel==2) ? 1.f : 0.f; w3 = (sel==3) ? 1.f : 0.f;
            w4 = (sel==4) ? 1.f : 0.f;
        }
        c1s[p] = w0 + w4 + 0.5f*(w2 + w3);
        c23[p] = make_float2(w1, 0.5f*(w2 - w3));
    }
    __syncthreads();
    // g_f = sum of c1 over pairs containing feature f  (pair idx(i,j) = i(i-1)/2 + j, i>j)
    if (tid < NF) {
        const int f = tid;
        float g = 0.f;
        for (int j = 0; j < f; ++j)       g += c1s[f*(f-1)/2 + j];
        for (int i = f+1; i < NF; ++i)    g += c1s[i*(i-1)/2 + f];
        gs[f] = g;
    }
    __syncthreads();

    const int wave = tid >> 6;
    const int lane = tid & 63;          // lane == embedding dim d
    const float bias = biasp[0];

    int sbase = (blockIdx.x * NWAVES + wave) * SPW;
    sbase = __builtin_amdgcn_readfirstlane(sbase);  // hint: wave-uniform

    // ---- gather: e[f] = emb2[f, x[s,f], lane]; first += emb1[f, x[s,f]] ----
    float e0[NF], e1r[NF];
    float first0 = 0.f, first1 = 0.f;
    #pragma unroll
    for (int f = 0; f < NF; ++f) {
        const int i0 = x[(sbase + 0) * NF + f];
        const int i1 = x[(sbase + 1) * NF + f];
        e0[f]  = emb2[(unsigned)(f * NV + i0) * 64u + (unsigned)lane];
        e1r[f] = emb2[(unsigned)(f * NV + i1) * 64u + (unsigned)lane];
        first0 += emb1[f * NV + i0];
        first1 += emb1[f * NV + i1];
    }

    // ---- linear (s_plus) term folded per lane: acc += sum_f g_f * e[f][d] ----
    float acc0 = 0.f, acc1 = 0.f;
    #pragma unroll
    for (int f = 0; f < NF; ++f) {
        const float g = gs[f];
        acc0 = fmaf(g, e0[f],  acc0);
        acc1 = fmaf(g, e1r[f], acc1);
    }

    // ---- pair loop: acc += c2 * e_i*e_j + c3 * |e_i - e_j|  (per lane d) ----
    int p = 0;
    #pragma unroll
    for (int i = 1; i < NF; ++i) {
        #pragma unroll
        for (int j = 0; j < i; ++j) {
            const float2 c = c23[p]; ++p;
            {
                const float prod = e0[i] * e0[j];
                const float diff = e0[i] - e0[j];
                acc0 = fmaf(c.x, prod, acc0);
                acc0 = fmaf(c.y, fabsf(diff), acc0);
            }
            {
                const float prod = e1r[i] * e1r[j];
                const float diff = e1r[i] - e1r[j];
                acc1 = fmaf(c.x, prod, acc1);
                acc1 = fmaf(c.y, fabsf(diff), acc1);
            }
        }
    }

    // ---- one wave reduction over d for both samples ----
    #pragma unroll
    for (int off = 32; off > 0; off >>= 1) {
        acc0 += __shfl_xor(acc0, off, 64);
        acc1 += __shfl_xor(acc1, off, 64);
    }

    const float z0 = acc0 + first0 + bias;
    const float z1 = acc1 + first1 + bias;
    if (lane == 0) {
        out[sbase + 0] = 1.f / (1.f + __expf(-z0));
        out[sbase + 1] = 1.f / (1.f + __expf(-z1));
    }
}

extern "C" void kernel_launch(void* const* d_in, const int* in_sizes, int n_in,
                              void* d_out, int out_size, void* d_ws, size_t ws_size,
                              hipStream_t stream) {
    const int*   x      = (const int*)d_in[0];
    const int*   flagp  = (const int*)d_in[1];
    const float* emb2   = (const float*)d_in[2];
    const float* emb1   = (const float*)d_in[3];
    const float* biasp  = (const float*)d_in[4];
    const float* arch_w = (const float*)d_in[5];
    float* outp = (float*)d_out;

    const int grid = NB / SPB;  // 8192 / 8 = 1024 blocks
    ofm_kernel<<<grid, BLOCK, 0, stream>>>(x, flagp, emb2, emb1, biasp, arch_w, outp);
}